// Round 11
// baseline (824.425 us; speedup 1.0000x reference)
//
#include <hip/hip_runtime.h>

#define IN_CH 128
#define HID   256
#define PB_VT 16            // 4096 edges per partition block

typedef __attribute__((ext_vector_type(8))) short bf16x8;
typedef __attribute__((ext_vector_type(4))) float f32x4;
typedef __attribute__((ext_vector_type(8))) unsigned short ushort8;

__device__ __forceinline__ ushort f2b(float f) {
    unsigned u = __float_as_uint(f);
    unsigned r = (u + 0x7fffu + ((u >> 16) & 1u)) >> 16;
    return (ushort)r;
}
__device__ __forceinline__ float b2f(ushort h) {
    return __uint_as_float(((unsigned)h) << 16);
}

// ================= atomic-free two-level counting sort =================
__global__ __launch_bounds__(256)
void part_hist_kernel(const int* __restrict__ dst, const int* __restrict__ edges,
                      int* __restrict__ histG, int* __restrict__ histP,
                      int E, int E2, int NBUK, int NBG) {
    __shared__ int hist[512];
    int t = threadIdx.x;
    bool isG = (int)blockIdx.x < NBG;
    int blk = isG ? blockIdx.x : blockIdx.x - NBG;
    for (int i = t; i < NBUK; i += 256) hist[i] = 0;
    __syncthreads();
    long long e0 = (long long)blk * (256 * PB_VT);
    if (isG) {
#pragma unroll
        for (int i = 0; i < PB_VT; i++) {
            long long e = e0 + i * 256 + t;
            if (e < E) atomicAdd(&hist[dst[e] >> 8], 1);
        }
    } else {
#pragma unroll
        for (int i = 0; i < PB_VT; i++) {
            long long e = e0 + i * 256 + t;
            if (e < E2) atomicAdd(&hist[edges[e * 2] >> 8], 1);
        }
    }
    __syncthreads();
    int* outp = isG ? histG : histP;
    for (int i = t; i < NBUK; i += 256) outp[(size_t)blk * NBUK + i] = hist[i];
}

__global__ __launch_bounds__(512)
void col_scan_kernel(const int* __restrict__ histG, const int* __restrict__ histP,
                     int* __restrict__ scanTG, int* __restrict__ scanTP,
                     int* __restrict__ totG, int* __restrict__ totP,
                     int NBUK, int NBG, int NBP) {
    __shared__ int s[512];
    int t = threadIdx.x;
    bool isG = (int)blockIdx.x < NBUK;
    int col = isG ? blockIdx.x : blockIdx.x - NBUK;
    const int* hist = isG ? histG : histP;
    int NBX = isG ? NBG : NBP;
    int v = (t < NBX) ? hist[(size_t)t * NBUK + col] : 0;
    s[t] = v;
    __syncthreads();
    for (int d = 1; d < 512; d <<= 1) {
        int u = (t >= d) ? s[t - d] : 0;
        __syncthreads(); s[t] += u; __syncthreads();
    }
    int* scanT = isG ? scanTG : scanTP;
    if (t < NBX) scanT[(size_t)col * NBX + t] = s[t] - v;
    if (t == 511) (isG ? totG : totP)[col] = s[511];
}

__global__ __launch_bounds__(512)
void bucket_scan_kernel(const int* __restrict__ totG, const int* __restrict__ totP,
                        int* __restrict__ startG, int* __restrict__ startP, int NBUK) {
    __shared__ int s[512];
    int t = threadIdx.x;
    int v = (t < NBUK) ? totG[t] : 0;
    s[t] = v; __syncthreads();
    for (int d = 1; d < 512; d <<= 1) { int u = (t >= d) ? s[t - d] : 0; __syncthreads(); s[t] += u; __syncthreads(); }
    if (t < NBUK) startG[t] = s[t] - v;
    __syncthreads();
    v = (t < NBUK) ? totP[t] : 0;
    s[t] = v; __syncthreads();
    for (int d = 1; d < 512; d <<= 1) { int u = (t >= d) ? s[t - d] : 0; __syncthreads(); s[t] += u; __syncthreads(); }
    if (t < NBUK) startP[t] = s[t] - v;
}

// Phase C: scatter into bucket-contiguous tmp (packed payloads).
__global__ __launch_bounds__(256)
void part_scatter_kernel(const int* __restrict__ src, const int* __restrict__ dst,
                         const int* __restrict__ edges,
                         const int* __restrict__ scanTG, const int* __restrict__ scanTP,
                         const int* __restrict__ startG, const int* __restrict__ startP,
                         unsigned* __restrict__ tmpG, unsigned long long* __restrict__ tmpP,
                         int E, int E2, int NBUK, int NBG, int NBP) {
    __shared__ int cur[512];
    int t = threadIdx.x;
    bool isG = (int)blockIdx.x < NBG;
    int blk = isG ? blockIdx.x : blockIdx.x - NBG;
    int NBX = isG ? NBG : NBP;
    const int* scanT = isG ? scanTG : scanTP;
    const int* bstart = isG ? startG : startP;
    for (int i = t; i < NBUK; i += 256)
        cur[i] = bstart[i] + scanT[(size_t)i * NBX + blk];
    __syncthreads();
    long long e0 = (long long)blk * (256 * PB_VT);
    if (isG) {
#pragma unroll
        for (int i = 0; i < PB_VT; i++) {
            long long e = e0 + i * 256 + t;
            if (e < E) {
                int d = dst[e];
                int pos = atomicAdd(&cur[d >> 8], 1);   // LDS atomic
                tmpG[pos] = ((unsigned)src[e] << 8) | (unsigned)(d & 255);
            }
        }
    } else {
#pragma unroll
        for (int i = 0; i < PB_VT; i++) {
            long long e = e0 + i * 256 + t;
            if (e < E2) {
                int2 ab = *(const int2*)(edges + e * 2);
                int pos = atomicAdd(&cur[ab.x >> 8], 1);
                tmpP[pos] = ((unsigned long long)(unsigned)(ab.x & 255) << 56)
                          | ((unsigned long long)(unsigned)ab.y << 32)
                          | (unsigned)e;
            }
        }
    }
}

__global__ __launch_bounds__(256)
void bucket_sort_kernel(const unsigned* __restrict__ tmpG, const unsigned long long* __restrict__ tmpP,
                        const int* __restrict__ startG, const int* __restrict__ totG,
                        const int* __restrict__ startP, const int* __restrict__ totP,
                        int* __restrict__ count, int* __restrict__ offs,
                        int* __restrict__ nbr, unsigned long long* __restrict__ pairs,
                        int N, int Npad, int NBUK) {
    __shared__ int h[256], loffs[256], lcur[256];
    int t = threadIdx.x;
    bool isG = (int)blockIdx.x < NBUK;
    int b = isG ? blockIdx.x : blockIdx.x - NBUK;
    int s = isG ? startG[b] : startP[b];
    int c = isG ? totG[b]   : totP[b];
    h[t] = 0;
    __syncthreads();
    if (isG) {
        for (int i = t; i < c; i += 256) atomicAdd(&h[tmpG[s + i] & 255], 1);
    } else {
        for (int i = t; i < c; i += 256) atomicAdd(&h[(int)(tmpP[s + i] >> 56)], 1);
    }
    __syncthreads();
    int v = h[t];
    loffs[t] = v;
    __syncthreads();
    for (int d = 1; d < 256; d <<= 1) {
        int u = (t >= d) ? loffs[t - d] : 0;
        __syncthreads(); loffs[t] += u; __syncthreads();
    }
    int excl = loffs[t] - v;
    lcur[t] = excl;
    int node = b * 256 + t;
    if (node < N) {
        int base = isG ? 0 : Npad;
        count[base + node] = v;
        offs[base + node] = s + excl;
    }
    __syncthreads();
    if (isG) {
        for (int i = t; i < c; i += 256) {
            unsigned w = tmpG[s + i];
            int p = atomicAdd(&lcur[w & 255], 1);
            nbr[s + p] = (int)(w >> 8);
        }
    } else {
        for (int i = t; i < c; i += 256) {
            unsigned long long w = tmpP[s + i];
            int p = atomicAdd(&lcur[(int)(w >> 56)], 1);
            pairs[s + p] = w & 0x00FFFFFFFFFFFFFFull;
        }
    }
}

// ================= bf16 conversions =================
__global__ void cvt_kernel(const float* __restrict__ in, ushort* __restrict__ o, int n4) {
    int i = blockIdx.x * 256 + threadIdx.x;
    if (i < n4) {
        float4 v = ((const float4*)in)[i];
        ushort4 u;
        u.x = f2b(v.x); u.y = f2b(v.y); u.z = f2b(v.z); u.w = f2b(v.w);
        ((ushort4*)o)[i] = u;
    }
}

template<bool PERM_K>
__global__ void prep_w_kernel(const float* __restrict__ Wl, const float* __restrict__ Wr,
                              ushort* __restrict__ Wt, int KH) {
    int ktot = 2 * KH;
    int idx = blockIdx.x * 256 + threadIdx.x;
    if (idx >= 256 * ktot) return;
    int n = idx / ktot, k = idx % ktot;
    int kh = (k < KH) ? k : (k - KH);
    int c = kh;
    if (PERM_K) {
        int j = kh & 63;
        c = (kh & ~63) | ((j & 3) * 16 + (j >> 2));
    }
    float v = (k < KH) ? Wl[(size_t)c * 256 + n] : Wr[(size_t)c * 256 + n];
    Wt[idx] = f2b(v);
}

// ================= fused gather-mean + MFMA GEMM =================
// Phase 1: each block gather-means its own 64 rows directly into LDS in MFMA
// fragment order (no agg round trip through HBM).
// Phase 2: 512-thread GEMM (8 waves, 32 AGPR acc); A-left fragments read from
// meanLds, A-right staged from hsrc self-rows, B from Wt with register prefetch.
// Output in P-permuted layout via LDS-bounced epilogue (as before).
template<int KH, bool RELU>
__global__ __launch_bounds__(512, 4)
void fused_sage(const ushort* __restrict__ hsrc,
                const int* __restrict__ nbr, const int* __restrict__ offs,
                const int* __restrict__ count,
                const ushort* __restrict__ Wt, const float* __restrict__ bias,
                ushort* __restrict__ out, int N) {
    constexpr int KTOT = 2 * KH;
    constexpr int MCH  = KH / 32;            // mean k-chunks (4 or 8)
    constexpr int GS   = KH / 8;             // gather group size (16 or 32)
    constexpr int NG   = 512 / GS;           // groups per block (32 or 16)
    __shared__ ushort smem[MCH * 2048 + 2048 + 8192];  // meanLds | As | Bs
    ushort* meanLds = smem;
    ushort* As = smem + MCH * 2048;
    ushort* Bs = As + 2048;

    const int t = threadIdx.x;
    const int rowBase = blockIdx.x * 64;

    // ---- phase 1: gather-mean into meanLds (fragment order) ----
    {
        const int g    = t / GS;
        const int gl   = t % GS;
        const int c    = gl >> 2;
        const int kkhi = gl & 3;
        for (int rr = g; rr < 64; rr += NG) {
            int node = rowBase + rr;
            float a0[8], a1[8];
#pragma unroll
            for (int i = 0; i < 8; i++) { a0[i] = 0.f; a1[i] = 0.f; }
            int cnt = 0;
            if (node < N) {
                int start = offs[node];
                cnt = count[node];
                int j = 0;
                for (; j + 1 < cnt; j += 2) {
                    int s0 = nbr[start + j], s1 = nbr[start + j + 1];
                    ushort8 v0 = *(const ushort8*)(hsrc + (size_t)s0 * KH + gl * 8);
                    ushort8 v1 = *(const ushort8*)(hsrc + (size_t)s1 * KH + gl * 8);
#pragma unroll
                    for (int i = 0; i < 8; i++) { a0[i] += b2f(v0[i]); a1[i] += b2f(v1[i]); }
                }
                if (j < cnt) {
                    int s0 = nbr[start + j];
                    ushort8 v0 = *(const ushort8*)(hsrc + (size_t)s0 * KH + gl * 8);
#pragma unroll
                    for (int i = 0; i < 8; i++) a0[i] += b2f(v0[i]);
                }
            }
            float sc = 1.0f / fmaxf((float)cnt, 1.0f);
            ushort8 o;
#pragma unroll
            for (int i = 0; i < 8; i++) o[i] = f2b((a0[i] + a1[i]) * sc);
            *(ushort8*)&meanLds[c * 2048 + ((rr >> 4) * 64 + (rr & 15) * 4 + kkhi) * 8] = o;
        }
    }
    // (first __syncthreads inside the K-loop publishes meanLds)

    // ---- phase 2: GEMM ----
    const int wave = t >> 6;
    const int lane = t & 63;
    const int quad = lane >> 4;
    const int l16  = lane & 15;

    const int aRow = t >> 3;
    const int aK   = (t & 7) * 4;
    const bool aRowOK = (rowBase + aRow) < N;
    const int aLds = ((aRow >> 4) * 64 + (aRow & 15) * 4 + (aK >> 3)) * 8 + (aK & 7);

    const int bN   = t >> 1;
    const int bCh0 = (t & 1) * 2;
    const int bFragBase = (bN >> 6) * 256 + ((bN >> 4) & 3) * 64 + (bN & 15) * 4;

    int bFrag[2];
#pragma unroll
    for (int nt = 0; nt < 2; nt++) {
        int c = wave * 32 + nt * 16 + l16;
        bFrag[nt] = ((c >> 6) * 256 + ((c >> 4) & 3) * 64 + (c & 15) * 4 + quad) * 8;
    }

    f32x4 acc[4][2];
#pragma unroll
    for (int i = 0; i < 4; i++)
#pragma unroll
        for (int j = 0; j < 2; j++) acc[i][j] = (f32x4)0.0f;

    unsigned long long aReg = 0ull;
    ulonglong2 bReg[2];
    bReg[0] = *(const ulonglong2*)(Wt + (size_t)bN * KTOT + bCh0 * 8);
    bReg[1] = *(const ulonglong2*)(Wt + (size_t)bN * KTOT + (bCh0 + 1) * 8);

    for (int k0 = 0; k0 < KTOT; k0 += 32) {
        __syncthreads();
        *(ulonglong2*)&Bs[(bFragBase + bCh0) * 8]     = bReg[0];
        *(ulonglong2*)&Bs[(bFragBase + bCh0 + 1) * 8] = bReg[1];
        if (k0 >= KH)
            *(unsigned long long*)&As[aLds] = aReg;

        int kn = k0 + 32;
        if (kn < KTOT) {
            bReg[0] = *(const ulonglong2*)(Wt + (size_t)bN * KTOT + kn + bCh0 * 8);
            bReg[1] = *(const ulonglong2*)(Wt + (size_t)bN * KTOT + kn + (bCh0 + 1) * 8);
            if (kn >= KH && aRowOK)
                aReg = *(const unsigned long long*)(hsrc + (size_t)(rowBase + aRow) * KH
                                                   + (kn - KH) + aK);
        }
        __syncthreads();

        const ushort* aBase = (k0 < KH) ? (meanLds + (k0 >> 5) * 2048) : As;
        bf16x8 af[4], bf[2];
#pragma unroll
        for (int mt = 0; mt < 4; mt++)
            af[mt] = *(const bf16x8*)&aBase[(mt * 64 + l16 * 4 + quad) * 8];
#pragma unroll
        for (int nt = 0; nt < 2; nt++)
            bf[nt] = *(const bf16x8*)&Bs[bFrag[nt]];
#pragma unroll
        for (int mt = 0; mt < 4; mt++)
#pragma unroll
            for (int nt = 0; nt < 2; nt++)
                acc[mt][nt] = __builtin_amdgcn_mfma_f32_16x16x32_bf16(
                    af[mt], bf[nt], acc[mt][nt], 0, 0, 0);
    }

    float bv[2];
#pragma unroll
    for (int nt = 0; nt < 2; nt++) bv[nt] = bias[wave * 32 + nt * 16 + l16]; // logical col
    ushort* tile = smem;                       // 32 x 256 shorts (meanLds region, dead now)

#pragma unroll
    for (int hf = 0; hf < 2; hf++) {
        __syncthreads();
#pragma unroll
        for (int mh = 0; mh < 2; mh++) {
            int mt = hf * 2 + mh;
#pragma unroll
            for (int reg = 0; reg < 4; reg++) {
                int rl = mh * 16 + quad * 4 + reg;
                float v0 = acc[mt][0][reg] + bv[0];
                float v1 = acc[mt][1][reg] + bv[1];
                if (RELU) { v0 = fmaxf(v0, 0.0f); v1 = fmaxf(v1, 0.0f); }
                ushort2 o;
                o.x = f2b(v0); o.y = f2b(v1);
                // P-permuted position: (c&~63) | (l16*4 + ((c>>4)&3))
                *(ushort2*)&tile[rl * 256 + (wave >> 1) * 64 + l16 * 4 + (wave & 1) * 2] = o;
            }
        }
        __syncthreads();
#pragma unroll
        for (int i = 0; i < 2; i++) {
            int ch = i * 512 + t;              // 1024 chunks of 16B
            int rl = ch >> 5, c16 = ch & 31;
            int row = rowBase + hf * 32 + rl;
            if (row < N)
                *(ushort8*)(out + (size_t)row * 256 + c16 * 8) =
                    *(const ushort8*)&tile[rl * 256 + c16 * 8];
        }
    }
}

// ================= decode: one wave per a-node, 4-deep per half =================
__global__ void decode2_kernel(const ushort* __restrict__ z,
                               const unsigned long long* __restrict__ pairs,
                               const int* __restrict__ offsA, const int* __restrict__ countA,
                               float* __restrict__ out, int N) {
    int a = blockIdx.x * 4 + (threadIdx.x >> 6);
    if (a >= N) return;
    int cnt = countA[a];
    if (cnt == 0) return;
    int lane = threadIdx.x & 63;
    int half = lane >> 5, hl = lane & 31;
    int start = offsA[a];

    float ar[8];
    {
        ushort8 va = *(const ushort8*)(z + (size_t)a * HID + hl * 8);
#pragma unroll
        for (int i = 0; i < 8; i++) ar[i] = b2f(va[i]);
    }

    int j = half;
    for (; j + 6 < cnt; j += 8) {
        unsigned long long p0 = pairs[start + j];
        unsigned long long p1 = pairs[start + j + 2];
        unsigned long long p2 = pairs[start + j + 4];
        unsigned long long p3 = pairs[start + j + 6];
        int b0 = (int)(p0 >> 32), e0 = (int)(p0 & 0xffffffffu);
        int b1 = (int)(p1 >> 32), e1 = (int)(p1 & 0xffffffffu);
        int b2 = (int)(p2 >> 32), e2 = (int)(p2 & 0xffffffffu);
        int b3 = (int)(p3 >> 32), e3 = (int)(p3 & 0xffffffffu);
        ushort8 v0 = *(const ushort8*)(z + (size_t)b0 * HID + hl * 8);
        ushort8 v1 = *(const ushort8*)(z + (size_t)b1 * HID + hl * 8);
        ushort8 v2 = *(const ushort8*)(z + (size_t)b2 * HID + hl * 8);
        ushort8 v3 = *(const ushort8*)(z + (size_t)b3 * HID + hl * 8);
        float s0 = 0.f, s1 = 0.f, s2 = 0.f, s3 = 0.f;
#pragma unroll
        for (int i = 0; i < 8; i++) {
            s0 = fmaf(ar[i], b2f(v0[i]), s0);
            s1 = fmaf(ar[i], b2f(v1[i]), s1);
            s2 = fmaf(ar[i], b2f(v2[i]), s2);
            s3 = fmaf(ar[i], b2f(v3[i]), s3);
        }
#pragma unroll
        for (int off = 1; off < 32; off <<= 1) {
            s0 += __shfl_xor(s0, off, 64);
            s1 += __shfl_xor(s1, off, 64);
            s2 += __shfl_xor(s2, off, 64);
            s3 += __shfl_xor(s3, off, 64);
        }
        if (hl == 0) { out[e0] = s0; out[e1] = s1; out[e2] = s2; out[e3] = s3; }
    }
    for (; j < cnt; j += 2) {
        unsigned long long p0 = pairs[start + j];
        int b0 = (int)(p0 >> 32), e0 = (int)(p0 & 0xffffffffu);
        ushort8 v0 = *(const ushort8*)(z + (size_t)b0 * HID + hl * 8);
        float s0 = 0.f;
#pragma unroll
        for (int i = 0; i < 8; i++) s0 = fmaf(ar[i], b2f(v0[i]), s0);
#pragma unroll
        for (int off = 1; off < 32; off <<= 1) s0 += __shfl_xor(s0, off, 64);
        if (hl == 0) out[e0] = s0;
    }
}

extern "C" void kernel_launch(void* const* d_in, const int* in_sizes, int n_in,
                              void* d_out, int out_size, void* d_ws, size_t ws_size,
                              hipStream_t stream) {
    const float* x    = (const float*)d_in[0];
    const int* eidx   = (const int*)d_in[1];
    const int* edges  = (const int*)d_in[2];
    const float* W1l  = (const float*)d_in[3];
    const float* b1   = (const float*)d_in[4];
    const float* W1r  = (const float*)d_in[5];
    const float* W2l  = (const float*)d_in[6];
    const float* b2   = (const float*)d_in[7];
    const float* W2r  = (const float*)d_in[8];
    float* out = (float*)d_out;

    const int N  = in_sizes[0] / IN_CH;
    const int E  = in_sizes[1] / 2;
    const int E2 = in_sizes[2] / 2;
    const int* src = eidx;
    const int* dst = eidx + E;

    const int NBUK = (N + 255) >> 8;            // 256-node buckets (<=512)
    const int Npad = NBUK << 8;
    const int NBG  = (E  + 256 * PB_VT - 1) / (256 * PB_VT);   // <=512
    const int NBP  = (E2 + 256 * PB_VT - 1) / (256 * PB_VT);

    int* count   = (int*)d_ws;
    int* offs    = count + 2 * Npad;
    int* histG   = offs + 2 * Npad;
    int* histP   = histG + (size_t)NBG * NBUK;
    int* scanTG  = histP + (size_t)NBP * NBUK;
    int* scanTP  = scanTG + (size_t)NBUK * NBG;
    int* totG    = scanTP + (size_t)NBUK * NBP;
    int* totP    = totG + 512;
    int* startG  = totP + 512;
    int* startP  = startG + 512;
    int* nbr     = startP + 512;
    size_t intWords = (size_t)(nbr - (int*)d_ws) + E;
    intWords = (intWords + 1) & ~(size_t)1;
    unsigned long long* pairs = (unsigned long long*)((int*)d_ws + intWords);
    ushort* xb  = (ushort*)(pairs + E2);
    ushort* h   = xb + (size_t)N * IN_CH;
    ushort* z   = h + (size_t)N * HID;
    ushort* Wt1 = z + (size_t)N * HID;
    ushort* Wt2 = Wt1 + 256 * 256;
    // packed tmp partition arrays overlay z (dead until fused gemm2 writes z)
    unsigned* tmpG = (unsigned*)z;
    unsigned long long* tmpP = (unsigned long long*)(tmpG + ((E + 1) & ~1));

    // ---- conversions ----
    cvt_kernel<<<((N * IN_CH / 4) + 255) / 256, 256, 0, stream>>>(x, xb, N * IN_CH / 4);
    prep_w_kernel<false><<<(256 * 256 + 255) / 256, 256, 0, stream>>>(W1l, W1r, Wt1, IN_CH);
    prep_w_kernel<true><<<(256 * 512 + 255) / 256, 256, 0, stream>>>(W2l, W2r, Wt2, HID);

    // ---- atomic-free two-level counting sorts ----
    part_hist_kernel<<<NBG + NBP, 256, 0, stream>>>(dst, edges, histG, histP, E, E2, NBUK, NBG);
    col_scan_kernel<<<2 * NBUK, 512, 0, stream>>>(histG, histP, scanTG, scanTP, totG, totP,
                                                  NBUK, NBG, NBP);
    bucket_scan_kernel<<<1, 512, 0, stream>>>(totG, totP, startG, startP, NBUK);
    part_scatter_kernel<<<NBG + NBP, 256, 0, stream>>>(src, dst, edges, scanTG, scanTP,
                                                       startG, startP, tmpG, tmpP,
                                                       E, E2, NBUK, NBG, NBP);
    bucket_sort_kernel<<<2 * NBUK, 256, 0, stream>>>(tmpG, tmpP,
                                                     startG, totG, startP, totP,
                                                     count, offs, nbr, pairs, N, Npad, NBUK);

    // ---- layer 1 (fused gather-mean + GEMM): h = relu([mean(x)|x] @ Wt1 + b1) ----
    fused_sage<IN_CH, true><<<(N + 63) / 64, 512, 0, stream>>>(
        xb, nbr, offs, count, Wt1, b1, h, N);

    // ---- layer 2 (fused): z = [mean(h)|h] @ Wt2 + b2 ----
    fused_sage<HID, false><<<(N + 63) / 64, 512, 0, stream>>>(
        h, nbr, offs, count, Wt2, b2, z, N);

    // ---- decode ----
    decode2_kernel<<<(N + 3) / 4, 256, 0, stream>>>(z, pairs, offs + Npad, count + Npad, out, N);
}

// Round 12
// 746.282 us; speedup vs baseline: 1.1047x; 1.1047x over previous
//
#include <hip/hip_runtime.h>

#define IN_CH 128
#define HID   256
#define PB_VT 16            // 4096 edges per partition block

typedef __attribute__((ext_vector_type(8))) short bf16x8;
typedef __attribute__((ext_vector_type(4))) float f32x4;
typedef __attribute__((ext_vector_type(8))) unsigned short ushort8;

__device__ __forceinline__ ushort f2b(float f) {
    unsigned u = __float_as_uint(f);
    unsigned r = (u + 0x7fffu + ((u >> 16) & 1u)) >> 16;
    return (ushort)r;
}
__device__ __forceinline__ float b2f(ushort h) {
    return __uint_as_float(((unsigned)h) << 16);
}

// ================= atomic-free two-level counting sort =================
__global__ __launch_bounds__(256)
void part_hist_kernel(const int* __restrict__ dst, const int* __restrict__ edges,
                      int* __restrict__ histG, int* __restrict__ histP,
                      int E, int E2, int NBUK, int NBG) {
    __shared__ int hist[512];
    int t = threadIdx.x;
    bool isG = (int)blockIdx.x < NBG;
    int blk = isG ? blockIdx.x : blockIdx.x - NBG;
    for (int i = t; i < NBUK; i += 256) hist[i] = 0;
    __syncthreads();
    long long e0 = (long long)blk * (256 * PB_VT);
    if (isG) {
#pragma unroll
        for (int i = 0; i < PB_VT; i++) {
            long long e = e0 + i * 256 + t;
            if (e < E) atomicAdd(&hist[dst[e] >> 8], 1);
        }
    } else {
#pragma unroll
        for (int i = 0; i < PB_VT; i++) {
            long long e = e0 + i * 256 + t;
            if (e < E2) atomicAdd(&hist[edges[e * 2] >> 8], 1);
        }
    }
    __syncthreads();
    int* outp = isG ? histG : histP;
    for (int i = t; i < NBUK; i += 256) outp[(size_t)blk * NBUK + i] = hist[i];
}

__global__ __launch_bounds__(512)
void col_scan_kernel(const int* __restrict__ histG, const int* __restrict__ histP,
                     int* __restrict__ scanTG, int* __restrict__ scanTP,
                     int* __restrict__ totG, int* __restrict__ totP,
                     int NBUK, int NBG, int NBP) {
    __shared__ int s[512];
    int t = threadIdx.x;
    bool isG = (int)blockIdx.x < NBUK;
    int col = isG ? blockIdx.x : blockIdx.x - NBUK;
    const int* hist = isG ? histG : histP;
    int NBX = isG ? NBG : NBP;
    int v = (t < NBX) ? hist[(size_t)t * NBUK + col] : 0;
    s[t] = v;
    __syncthreads();
    for (int d = 1; d < 512; d <<= 1) {
        int u = (t >= d) ? s[t - d] : 0;
        __syncthreads(); s[t] += u; __syncthreads();
    }
    int* scanT = isG ? scanTG : scanTP;
    if (t < NBX) scanT[(size_t)col * NBX + t] = s[t] - v;
    if (t == 511) (isG ? totG : totP)[col] = s[511];
}

__global__ __launch_bounds__(512)
void bucket_scan_kernel(const int* __restrict__ totG, const int* __restrict__ totP,
                        int* __restrict__ startG, int* __restrict__ startP, int NBUK) {
    __shared__ int s[512];
    int t = threadIdx.x;
    int v = (t < NBUK) ? totG[t] : 0;
    s[t] = v; __syncthreads();
    for (int d = 1; d < 512; d <<= 1) { int u = (t >= d) ? s[t - d] : 0; __syncthreads(); s[t] += u; __syncthreads(); }
    if (t < NBUK) startG[t] = s[t] - v;
    __syncthreads();
    v = (t < NBUK) ? totP[t] : 0;
    s[t] = v; __syncthreads();
    for (int d = 1; d < 512; d <<= 1) { int u = (t >= d) ? s[t - d] : 0; __syncthreads(); s[t] += u; __syncthreads(); }
    if (t < NBUK) startP[t] = s[t] - v;
}

// Phase C: scatter into bucket-contiguous tmp (packed payloads).
__global__ __launch_bounds__(256)
void part_scatter_kernel(const int* __restrict__ src, const int* __restrict__ dst,
                         const int* __restrict__ edges,
                         const int* __restrict__ scanTG, const int* __restrict__ scanTP,
                         const int* __restrict__ startG, const int* __restrict__ startP,
                         unsigned* __restrict__ tmpG, unsigned long long* __restrict__ tmpP,
                         int E, int E2, int NBUK, int NBG, int NBP) {
    __shared__ int cur[512];
    int t = threadIdx.x;
    bool isG = (int)blockIdx.x < NBG;
    int blk = isG ? blockIdx.x : blockIdx.x - NBG;
    int NBX = isG ? NBG : NBP;
    const int* scanT = isG ? scanTG : scanTP;
    const int* bstart = isG ? startG : startP;
    for (int i = t; i < NBUK; i += 256)
        cur[i] = bstart[i] + scanT[(size_t)i * NBX + blk];
    __syncthreads();
    long long e0 = (long long)blk * (256 * PB_VT);
    if (isG) {
#pragma unroll
        for (int i = 0; i < PB_VT; i++) {
            long long e = e0 + i * 256 + t;
            if (e < E) {
                int d = dst[e];
                int pos = atomicAdd(&cur[d >> 8], 1);   // LDS atomic
                tmpG[pos] = ((unsigned)src[e] << 8) | (unsigned)(d & 255);
            }
        }
    } else {
#pragma unroll
        for (int i = 0; i < PB_VT; i++) {
            long long e = e0 + i * 256 + t;
            if (e < E2) {
                int2 ab = *(const int2*)(edges + e * 2);
                int pos = atomicAdd(&cur[ab.x >> 8], 1);
                tmpP[pos] = ((unsigned long long)(unsigned)(ab.x & 255) << 56)
                          | ((unsigned long long)(unsigned)ab.y << 32)
                          | (unsigned)e;
            }
        }
    }
}

// Phase D: per-bucket fine sort. Pair output packs (a<<38)|(b<<21)|e
// (a<2^17, b<2^17, e<2^21 for this problem size) so decode can run flat.
__global__ __launch_bounds__(256)
void bucket_sort_kernel(const unsigned* __restrict__ tmpG, const unsigned long long* __restrict__ tmpP,
                        const int* __restrict__ startG, const int* __restrict__ totG,
                        const int* __restrict__ startP, const int* __restrict__ totP,
                        int* __restrict__ count, int* __restrict__ offs,
                        int* __restrict__ nbr, unsigned long long* __restrict__ pairs,
                        int N, int Npad, int NBUK) {
    __shared__ int h[256], loffs[256], lcur[256];
    int t = threadIdx.x;
    bool isG = (int)blockIdx.x < NBUK;
    int b = isG ? blockIdx.x : blockIdx.x - NBUK;
    int s = isG ? startG[b] : startP[b];
    int c = isG ? totG[b]   : totP[b];
    h[t] = 0;
    __syncthreads();
    if (isG) {
        for (int i = t; i < c; i += 256) atomicAdd(&h[tmpG[s + i] & 255], 1);
    } else {
        for (int i = t; i < c; i += 256) atomicAdd(&h[(int)(tmpP[s + i] >> 56)], 1);
    }
    __syncthreads();
    int v = h[t];
    loffs[t] = v;
    __syncthreads();
    for (int d = 1; d < 256; d <<= 1) {
        int u = (t >= d) ? loffs[t - d] : 0;
        __syncthreads(); loffs[t] += u; __syncthreads();
    }
    int excl = loffs[t] - v;
    lcur[t] = excl;
    int node = b * 256 + t;
    if (node < N) {
        int base = isG ? 0 : Npad;
        count[base + node] = v;
        offs[base + node] = s + excl;
    }
    __syncthreads();
    if (isG) {
        for (int i = t; i < c; i += 256) {
            unsigned w = tmpG[s + i];
            int p = atomicAdd(&lcur[w & 255], 1);
            nbr[s + p] = (int)(w >> 8);
        }
    } else {
        for (int i = t; i < c; i += 256) {
            unsigned long long w = tmpP[s + i];
            int fine = (int)(w >> 56);
            int p = atomicAdd(&lcur[fine], 1);
            unsigned long long a  = (unsigned long long)(b * 256 + fine);
            unsigned long long bb = (w >> 32) & 0xFFFFFFull;
            unsigned long long e  = w & 0x1FFFFFull;
            pairs[s + p] = (a << 38) | (bb << 21) | e;
        }
    }
}

// ================= bf16 conversions =================
__global__ void cvt_kernel(const float* __restrict__ in, ushort* __restrict__ o, int n4) {
    int i = blockIdx.x * 256 + threadIdx.x;
    if (i < n4) {
        float4 v = ((const float4*)in)[i];
        ushort4 u;
        u.x = f2b(v.x); u.y = f2b(v.y); u.z = f2b(v.z); u.w = f2b(v.w);
        ((ushort4*)o)[i] = u;
    }
}

template<bool PERM_K>
__global__ void prep_w_kernel(const float* __restrict__ Wl, const float* __restrict__ Wr,
                              ushort* __restrict__ Wt, int KH) {
    int ktot = 2 * KH;
    int idx = blockIdx.x * 256 + threadIdx.x;
    if (idx >= 256 * ktot) return;
    int n = idx / ktot, k = idx % ktot;
    int kh = (k < KH) ? k : (k - KH);
    int c = kh;
    if (PERM_K) {
        int j = kh & 63;
        c = (kh & ~63) | ((j & 3) * 16 + (j >> 2));
    }
    float v = (k < KH) ? Wl[(size_t)c * 256 + n] : Wr[(size_t)c * 256 + n];
    Wt[idx] = f2b(v);
}

// ================= gather-mean aggregation =================
__global__ void agg1_kernel(const ushort* __restrict__ xb, const int* __restrict__ nbr,
                            const int* __restrict__ offs, const int* __restrict__ count,
                            ushort* __restrict__ agg, int N) {
    int w = blockIdx.x * 4 + (threadIdx.x >> 6);
    if (w >= N) return;
    int lane = threadIdx.x & 63;
    int grp = lane >> 4, gl = lane & 15;
    int start = offs[w], cnt = count[w];
    float a0[8], a1[8];
#pragma unroll
    for (int i = 0; i < 8; i++) { a0[i] = 0.0f; a1[i] = 0.0f; }
    int j = grp;
    for (; j + 4 < cnt; j += 8) {
        int s0 = nbr[start + j];
        int s1 = nbr[start + j + 4];
        ushort8 v0 = *(const ushort8*)(xb + (size_t)s0 * IN_CH + gl * 8);
        ushort8 v1 = *(const ushort8*)(xb + (size_t)s1 * IN_CH + gl * 8);
#pragma unroll
        for (int i = 0; i < 8; i++) { a0[i] += b2f(v0[i]); a1[i] += b2f(v1[i]); }
    }
    if (j < cnt) {
        int s0 = nbr[start + j];
        ushort8 v0 = *(const ushort8*)(xb + (size_t)s0 * IN_CH + gl * 8);
#pragma unroll
        for (int i = 0; i < 8; i++) a0[i] += b2f(v0[i]);
    }
#pragma unroll
    for (int i = 0; i < 8; i++) {
        a0[i] += a1[i];
        a0[i] += __shfl_xor(a0[i], 16, 64);
        a0[i] += __shfl_xor(a0[i], 32, 64);
    }
    if (grp == 0) {
        float r = 1.0f / fmaxf((float)cnt, 1.0f);
        ushort8 o;
#pragma unroll
        for (int i = 0; i < 8; i++) o[i] = f2b(a0[i] * r);
        *(ushort8*)(agg + (size_t)w * IN_CH + gl * 8) = o;
    }
}

__global__ void agg2_kernel(const ushort* __restrict__ h, const int* __restrict__ nbr,
                            const int* __restrict__ offs, const int* __restrict__ count,
                            ushort* __restrict__ agg, int N) {
    int w = blockIdx.x * 4 + (threadIdx.x >> 6);
    if (w >= N) return;
    int lane = threadIdx.x & 63;
    int half = lane >> 5, hl = lane & 31;
    int start = offs[w], cnt = count[w];
    float a0[8], a1[8];
#pragma unroll
    for (int i = 0; i < 8; i++) { a0[i] = 0.0f; a1[i] = 0.0f; }
    int j = half;
    for (; j + 6 < cnt; j += 8) {
        int s0 = nbr[start + j];
        int s1 = nbr[start + j + 2];
        int s2 = nbr[start + j + 4];
        int s3 = nbr[start + j + 6];
        ushort8 v0 = *(const ushort8*)(h + (size_t)s0 * HID + hl * 8);
        ushort8 v1 = *(const ushort8*)(h + (size_t)s1 * HID + hl * 8);
        ushort8 v2 = *(const ushort8*)(h + (size_t)s2 * HID + hl * 8);
        ushort8 v3 = *(const ushort8*)(h + (size_t)s3 * HID + hl * 8);
#pragma unroll
        for (int i = 0; i < 8; i++) {
            a0[i] += b2f(v0[i]) + b2f(v2[i]);
            a1[i] += b2f(v1[i]) + b2f(v3[i]);
        }
    }
    for (; j < cnt; j += 2) {
        int s0 = nbr[start + j];
        ushort8 v0 = *(const ushort8*)(h + (size_t)s0 * HID + hl * 8);
#pragma unroll
        for (int i = 0; i < 8; i++) a0[i] += b2f(v0[i]);
    }
#pragma unroll
    for (int i = 0; i < 8; i++) {
        a0[i] += a1[i];
        a0[i] += __shfl_xor(a0[i], 32, 64);
    }
    if (half == 0) {
        float r = 1.0f / fmaxf((float)cnt, 1.0f);
        ushort8 o;
#pragma unroll
        for (int i = 0; i < 8; i++) o[i] = f2b(a0[i] * r);
        *(ushort8*)(agg + (size_t)w * HID + hl * 8) = o;
    }
}

// ================= MFMA GEMM: 512 threads, 32 AGPR acc (round-10 proven) =================
template<int KTOT, bool RELU>
__global__ __launch_bounds__(512, 4)
void sage_gemm_mfma(const ushort* __restrict__ Aleft, const ushort* __restrict__ Aright,
                    const ushort* __restrict__ Wt, const float* __restrict__ bias,
                    ushort* __restrict__ out, int N) {
    constexpr int KH = KTOT / 2;
    __shared__ ushort smem[2048 + 8192];       // As[2048] | Bs[8192]
    ushort* As = smem;
    ushort* Bs = smem + 2048;

    const int t = threadIdx.x;                 // 0..511
    const int wave = t >> 6;                   // 0..7
    const int lane = t & 63;
    const int quad = lane >> 4;
    const int l16  = lane & 15;
    const int rowBase = blockIdx.x * 64;

    const int aRow = t >> 3;
    const int aK   = (t & 7) * 4;
    const bool aRowOK = (rowBase + aRow) < N;
    const int aLds = ((aRow >> 4) * 64 + (aRow & 15) * 4 + (aK >> 3)) * 8 + (aK & 7);

    const int bN   = t >> 1;
    const int bCh0 = (t & 1) * 2;
    const int bFragBase = (bN >> 6) * 256 + ((bN >> 4) & 3) * 64 + (bN & 15) * 4;

    int bFrag[2];
#pragma unroll
    for (int nt = 0; nt < 2; nt++) {
        int c = wave * 32 + nt * 16 + l16;
        bFrag[nt] = ((c >> 6) * 256 + ((c >> 4) & 3) * 64 + (c & 15) * 4 + quad) * 8;
    }

    f32x4 acc[4][2];
#pragma unroll
    for (int i = 0; i < 4; i++)
#pragma unroll
        for (int j = 0; j < 2; j++) acc[i][j] = (f32x4)0.0f;

    unsigned long long aReg = 0ull;
    ulonglong2 bReg[2];
    if (aRowOK)
        aReg = *(const unsigned long long*)(Aleft + (size_t)(rowBase + aRow) * KH + aK);
    bReg[0] = *(const ulonglong2*)(Wt + (size_t)bN * KTOT + bCh0 * 8);
    bReg[1] = *(const ulonglong2*)(Wt + (size_t)bN * KTOT + (bCh0 + 1) * 8);

    for (int k0 = 0; k0 < KTOT; k0 += 32) {
        __syncthreads();
        *(unsigned long long*)&As[aLds] = aReg;
        *(ulonglong2*)&Bs[(bFragBase + bCh0) * 8]     = bReg[0];
        *(ulonglong2*)&Bs[(bFragBase + bCh0 + 1) * 8] = bReg[1];

        int kn = k0 + 32;
        if (kn < KTOT) {
            if (aRowOK) {
                const ushort* Ap = (kn < KH)
                    ? (Aleft  + (size_t)(rowBase + aRow) * KH + (kn + aK))
                    : (Aright + (size_t)(rowBase + aRow) * KH + (kn - KH + aK));
                aReg = *(const unsigned long long*)Ap;
            }
            bReg[0] = *(const ulonglong2*)(Wt + (size_t)bN * KTOT + kn + bCh0 * 8);
            bReg[1] = *(const ulonglong2*)(Wt + (size_t)bN * KTOT + kn + (bCh0 + 1) * 8);
        }
        __syncthreads();

        bf16x8 af[4], bf[2];
#pragma unroll
        for (int mt = 0; mt < 4; mt++)
            af[mt] = *(const bf16x8*)&As[(mt * 64 + l16 * 4 + quad) * 8];
#pragma unroll
        for (int nt = 0; nt < 2; nt++)
            bf[nt] = *(const bf16x8*)&Bs[bFrag[nt]];
#pragma unroll
        for (int mt = 0; mt < 4; mt++)
#pragma unroll
            for (int nt = 0; nt < 2; nt++)
                acc[mt][nt] = __builtin_amdgcn_mfma_f32_16x16x32_bf16(
                    af[mt], bf[nt], acc[mt][nt], 0, 0, 0);
    }

    float bv[2];
#pragma unroll
    for (int nt = 0; nt < 2; nt++) bv[nt] = bias[wave * 32 + nt * 16 + l16]; // logical col
    ushort* tile = smem;                       // 32 x 256 shorts

#pragma unroll
    for (int hf = 0; hf < 2; hf++) {
        __syncthreads();
#pragma unroll
        for (int mh = 0; mh < 2; mh++) {
            int mt = hf * 2 + mh;
#pragma unroll
            for (int reg = 0; reg < 4; reg++) {
                int rl = mh * 16 + quad * 4 + reg;
                float v0 = acc[mt][0][reg] + bv[0];
                float v1 = acc[mt][1][reg] + bv[1];
                if (RELU) { v0 = fmaxf(v0, 0.0f); v1 = fmaxf(v1, 0.0f); }
                ushort2 o;
                o.x = f2b(v0); o.y = f2b(v1);
                *(ushort2*)&tile[rl * 256 + (wave >> 1) * 64 + l16 * 4 + (wave & 1) * 2] = o;
            }
        }
        __syncthreads();
#pragma unroll
        for (int i = 0; i < 2; i++) {
            int ch = i * 512 + t;
            int rl = ch >> 5, c16 = ch & 31;
            int row = rowBase + hf * 32 + rl;
            if (row < N)
                *(ushort8*)(out + (size_t)row * 256 + c16 * 8) =
                    *(const ushort8*)&tile[rl * 256 + c16 * 8];
        }
    }
}

// ================= decode v3: FLAT over packed pairs =================
// pairs[i] = (a<<38)|(b<<21)|e. Each 32-lane group does 4 pairs straight-line
// (8 row-loads in flight; a-rows are L1/L2 hits since pairs are a-sorted).
__global__ __launch_bounds__(256)
void decode3_kernel(const ushort* __restrict__ z,
                    const unsigned long long* __restrict__ pairs,
                    float* __restrict__ out, int E2) {
    int g  = blockIdx.x * 8 + (threadIdx.x >> 5);
    int hl = threadIdx.x & 31;
    long long base = (long long)g * 4;
    if (base >= E2) return;

    unsigned long long p[4];
    int nv = (int)((E2 - base) < 4 ? (E2 - base) : 4);
#pragma unroll
    for (int q = 0; q < 4; q++)
        p[q] = pairs[base + ((q < nv) ? q : 0)];

    float s[4] = {0.f, 0.f, 0.f, 0.f};
    ushort8 va[4], vb[4];
#pragma unroll
    for (int q = 0; q < 4; q++) {
        int a = (int)(p[q] >> 38);
        int b = (int)((p[q] >> 21) & 0x1FFFF);
        va[q] = *(const ushort8*)(z + (size_t)a * HID + hl * 8);
        vb[q] = *(const ushort8*)(z + (size_t)b * HID + hl * 8);
    }
#pragma unroll
    for (int q = 0; q < 4; q++)
#pragma unroll
        for (int i = 0; i < 8; i++)
            s[q] = fmaf(b2f(va[q][i]), b2f(vb[q][i]), s[q]);
#pragma unroll
    for (int off = 1; off < 32; off <<= 1) {
#pragma unroll
        for (int q = 0; q < 4; q++)
            s[q] += __shfl_xor(s[q], off, 64);
    }
    if (hl == 0) {
#pragma unroll
        for (int q = 0; q < 4; q++)
            if (q < nv) out[(int)(p[q] & 0x1FFFFF)] = s[q];
    }
}

extern "C" void kernel_launch(void* const* d_in, const int* in_sizes, int n_in,
                              void* d_out, int out_size, void* d_ws, size_t ws_size,
                              hipStream_t stream) {
    const float* x    = (const float*)d_in[0];
    const int* eidx   = (const int*)d_in[1];
    const int* edges  = (const int*)d_in[2];
    const float* W1l  = (const float*)d_in[3];
    const float* b1   = (const float*)d_in[4];
    const float* W1r  = (const float*)d_in[5];
    const float* W2l  = (const float*)d_in[6];
    const float* b2   = (const float*)d_in[7];
    const float* W2r  = (const float*)d_in[8];
    float* out = (float*)d_out;

    const int N  = in_sizes[0] / IN_CH;
    const int E  = in_sizes[1] / 2;
    const int E2 = in_sizes[2] / 2;
    const int* src = eidx;
    const int* dst = eidx + E;

    const int NBUK = (N + 255) >> 8;            // 256-node buckets (<=512)
    const int Npad = NBUK << 8;
    const int NBG  = (E  + 256 * PB_VT - 1) / (256 * PB_VT);   // <=512
    const int NBP  = (E2 + 256 * PB_VT - 1) / (256 * PB_VT);

    int* count   = (int*)d_ws;
    int* offs    = count + 2 * Npad;
    int* histG   = offs + 2 * Npad;
    int* histP   = histG + (size_t)NBG * NBUK;
    int* scanTG  = histP + (size_t)NBP * NBUK;
    int* scanTP  = scanTG + (size_t)NBUK * NBG;
    int* totG    = scanTP + (size_t)NBUK * NBP;
    int* totP    = totG + 512;
    int* startG  = totP + 512;
    int* startP  = startG + 512;
    int* nbr     = startP + 512;
    size_t intWords = (size_t)(nbr - (int*)d_ws) + E;
    intWords = (intWords + 1) & ~(size_t)1;
    unsigned long long* pairs = (unsigned long long*)((int*)d_ws + intWords);
    ushort* xb    = (ushort*)(pairs + E2);
    ushort* agg1b = xb + (size_t)N * IN_CH;
    ushort* agg2b = xb;                         // overlay after gemm1
    ushort* h     = agg1b + (size_t)N * IN_CH;
    ushort* z     = h + (size_t)N * HID;
    ushort* Wt1   = z + (size_t)N * HID;
    ushort* Wt2   = Wt1 + 256 * 256;
    // packed tmp partition arrays overlay z (dead until gemm2)
    unsigned* tmpG = (unsigned*)z;
    unsigned long long* tmpP = (unsigned long long*)(tmpG + ((E + 1) & ~1));

    // ---- conversions ----
    cvt_kernel<<<((N * IN_CH / 4) + 255) / 256, 256, 0, stream>>>(x, xb, N * IN_CH / 4);
    prep_w_kernel<false><<<(256 * 256 + 255) / 256, 256, 0, stream>>>(W1l, W1r, Wt1, IN_CH);
    prep_w_kernel<true><<<(256 * 512 + 255) / 256, 256, 0, stream>>>(W2l, W2r, Wt2, HID);

    // ---- atomic-free two-level counting sorts ----
    part_hist_kernel<<<NBG + NBP, 256, 0, stream>>>(dst, edges, histG, histP, E, E2, NBUK, NBG);
    col_scan_kernel<<<2 * NBUK, 512, 0, stream>>>(histG, histP, scanTG, scanTP, totG, totP,
                                                  NBUK, NBG, NBP);
    bucket_scan_kernel<<<1, 512, 0, stream>>>(totG, totP, startG, startP, NBUK);
    part_scatter_kernel<<<NBG + NBP, 256, 0, stream>>>(src, dst, edges, scanTG, scanTP,
                                                       startG, startP, tmpG, tmpP,
                                                       E, E2, NBUK, NBG, NBP);
    bucket_sort_kernel<<<2 * NBUK, 256, 0, stream>>>(tmpG, tmpP,
                                                     startG, totG, startP, totP,
                                                     count, offs, nbr, pairs, N, Npad, NBUK);

    // ---- layer 1 ----
    agg1_kernel<<<(N + 3) / 4, 256, 0, stream>>>(xb, nbr, offs, count, agg1b, N);
    sage_gemm_mfma<2 * IN_CH, true><<<(N + 63) / 64, 512, 0, stream>>>(
        agg1b, xb, Wt1, b1, h, N);

    // ---- layer 2 ----
    agg2_kernel<<<(N + 3) / 4, 256, 0, stream>>>(h, nbr, offs, count, agg2b, N);
    sage_gemm_mfma<2 * HID, false><<<(N + 63) / 64, 512, 0, stream>>>(
        agg2b, h, Wt2, b2, z, N);

    // ---- decode (flat over packed pairs) ----
    decode3_kernel<<<(E2 + 31) / 32, 256, 0, stream>>>(z, pairs, out, E2);
}